// Round 19
// baseline (49.610 us; speedup 1.0000x reference)
//
#include <hip/hip_runtime.h>
#include <cstdint>
#include <cstddef>

typedef unsigned short u16;
typedef __attribute__((ext_vector_type(8))) short short8;
typedef __attribute__((ext_vector_type(4))) float f32x4;

__device__ __forceinline__ u16 f2bf(float f){
  union { float f; unsigned u; } c; c.f = f;
  unsigned u = c.u;
  u += 0x7fffu + ((u >> 16) & 1u);   // RNE
  return (u16)(u >> 16);
}
__device__ __forceinline__ unsigned pk2(float a, float b){
  union { float f; unsigned u; } ca, cb; ca.f = a; cb.f = b;
  return ((ca.u + 0x8000u) >> 16) | ((cb.u + 0x8000u) & 0xFFFF0000u);
}

// xT2 layout: [b][row 0..65][col 0..65][128ci] bf16, interior at (h+1, w+1).
#define XB_STRIDE 557568   // 66*66*128 (u16 elements)
#define XR_STRIDE 8448     // 66*128

// wcomb layout (u16): b*147456 + ((tap*4+q)<<12) + (co<<5) + ciq
//   where ci = q*32 + ciq. One (tap,q) slab = 128co x 32ci = 8KB, linear.
//   Half-slab for co-half wcv starts at +wcv*2048 u16.

// direct-to-LDS 16B async copy
#define GLD_LDS(gsrc, ldst) \
  __builtin_amdgcn_global_load_lds((const __attribute__((address_space(1))) void*)(gsrc), \
                                   (__attribute__((address_space(3))) void*)(ldst), 16, 0, 0)

// raw barrier WITHOUT the implicit vmcnt(0) drain of __syncthreads()
#define BAR { asm volatile("s_waitcnt lgkmcnt(0)" ::: "memory"); \
              __builtin_amdgcn_s_barrier(); }
#define WAIT_VM(N) asm volatile("s_waitcnt vmcnt(" #N ")" ::: "memory")

// ---------------------------------------------------------------------------
// Kernel 1 (r18 version): transpose x -> padded xT2 bf16 + SE pool partials.
// grid 1024 (4 blocks/CU), b = bid&15 (bid%8==b%8 homing).
// ---------------------------------------------------------------------------
__global__ __launch_bounds__(256) void xpose_pool(
    const float* __restrict__ x, u16* __restrict__ xT2, float* __restrict__ part)
{
  const int bid = blockIdx.x;
  const int b = bid & 15, chunk = bid >> 4;   // chunk 0..63
  const int pos0 = chunk << 6;
  const int tid = threadIdx.x;
  __shared__ u16 tile[8192];         // 16 KB
  __shared__ float psum[128 * 17];   // 8.7 KB
  const float* xb = x + ((size_t)b << 19) + pos0;
  const int rq = tid & 15;           // row-quad
  const int p4 = rq << 2;
  const int gci = tid >> 4;          // granule 0..15

  if (chunk == 0){                   // fused halo zeroing (disjoint from interior)
    u16* xh = xT2 + (size_t)b * XB_STRIDE;
    for (int i = tid; i < 4160; i += 256){     // 260 pos * 16 granules
      const int p = i >> 4, oct = i & 15;
      int row, col;
      if (p < 66)      { row = 0;        col = p; }
      else if (p < 132){ row = 65;       col = p - 66; }
      else if (p < 196){ row = p - 131;  col = 0; }
      else             { row = p - 195;  col = 65; }
      *(uint4*)(xh + row * XR_STRIDE + (col << 7) + (oct << 3)) =
          make_uint4(0u, 0u, 0u, 0u);
    }
  }

  {
    const int ci8 = gci << 3;
    float4 L[8];
    #pragma unroll
    for (int j = 0; j < 8; ++j)
      L[j] = *(const float4*)(xb + ((size_t)(ci8 + j) << 12) + p4);
    #pragma unroll
    for (int j = 0; j < 8; ++j)
      psum[(ci8 + j) * 17 + rq] = L[j].x + L[j].y + L[j].z + L[j].w;
    const int gs = gci ^ (rq & 7);
    const float* e = (const float*)L;
    #pragma unroll
    for (int p = 0; p < 4; ++p){
      const int row = p4 + p;
      uint4 V;
      V.x = pk2(e[0 * 4 + p], e[1 * 4 + p]);
      V.y = pk2(e[2 * 4 + p], e[3 * 4 + p]);
      V.z = pk2(e[4 * 4 + p], e[5 * 4 + p]);
      V.w = pk2(e[6 * 4 + p], e[7 * 4 + p]);
      *(uint4*)(tile + (row << 7) + (gs << 3)) = V;
    }
  }
  __syncthreads();

  if (tid < 128){
    float s = 0.f;
    #pragma unroll
    for (int j = 0; j < 16; ++j) s += psum[tid * 17 + j];
    part[(((b << 6) | chunk) << 7) + tid] = s;
  }

  u16* xo = xT2 + (size_t)b * XB_STRIDE;
  const int g = tid & 15, rb = (tid >> 4) << 2;
  #pragma unroll
  for (int r = 0; r < 4; ++r){
    const int row = rb + r;
    const int gs = g ^ ((row >> 2) & 7);
    uint4 v = *(const uint4*)(tile + (row << 7) + (gs << 3));
    const int pos = pos0 + row;
    const int h = pos >> 6, w = pos & 63;
    *(uint4*)(xo + (h + 1) * XR_STRIDE + ((w + 1) << 7) + (g << 3)) = v;
  }
}

// ---------------------------------------------------------------------------
// Kernel 2 (r18 version): combine + inline attn, W staged via gld_lds under
// the attn compute. grid 1024 = cp*16 + b (bid%8==b%8 homing).
// ---------------------------------------------------------------------------
__global__ __launch_bounds__(256) void combine(
    const float* __restrict__ W, const float* __restrict__ bias,
    const float* __restrict__ part, const float* __restrict__ w1,
    const float* __restrict__ w2, const float* __restrict__ b2,
    u16* __restrict__ wcomb, float* __restrict__ bcomb)
{
  __shared__ float wlds[9216];   // [k][co_l][1152]
  __shared__ float sp[128];
  __shared__ float sh[33];
  __shared__ float sat[4];
  const int bid = blockIdx.x;
  const int b = bid & 15, cp = bid >> 4;    // cp: co-pair 0..63
  const int tid = threadIdx.x;

  #pragma unroll
  for (int it = 0; it < 9; ++it){
    const int G = it * 256 + tid;
    const int k = G / 576, rem = G - k * 576;
    const int co_l = rem / 288, j4 = rem - co_l * 288;
    const float* src = W + (size_t)(k * 128 + (cp << 1) + co_l) * 1152 + (j4 << 2);
    GLD_LDS(src, (char*)wlds + (G << 4));
  }

  // ---- inline attn[b]: pool (64 chunks) -> fc1 -> relu -> fc2 -> softmax ----
  if (tid < 128){
    const float* pb = part + (b << 13);
    float s = 0.f;
    #pragma unroll 8
    for (int c = 0; c < 64; ++c) s += pb[(c << 7) + tid];
    sp[tid] = s * (1.f / 4096.f);
  }
  __syncthreads();
  if (tid < 33){
    float h = 0.f;
    for (int ci = 0; ci < 128; ++ci) h += sp[ci] * w1[tid * 128 + ci];
    sh[tid] = fmaxf(h, 0.f);
  }
  __syncthreads();
  if (tid == 0){
    float l[4];
    #pragma unroll
    for (int t = 0; t < 4; ++t){
      float v = b2[t];
      for (int j = 0; j < 33; ++j) v += sh[j] * w2[t * 33 + j];
      l[t] = v * (1.f / 30.f);
    }
    float m = fmaxf(fmaxf(l[0], l[1]), fmaxf(l[2], l[3]));
    float e0 = __expf(l[0] - m), e1 = __expf(l[1] - m);
    float e2 = __expf(l[2] - m), e3 = __expf(l[3] - m);
    float inv = 1.f / (e0 + e1 + e2 + e3);
    sat[0] = e0 * inv; sat[1] = e1 * inv; sat[2] = e2 * inv; sat[3] = e3 * inv;
  }
  asm volatile("s_waitcnt vmcnt(0)" ::: "memory");
  __syncthreads();
  const float a0 = sat[0], a1 = sat[1], a2 = sat[2], a3 = sat[3];

  if (tid < 2){
    const int co = (cp << 1) + tid;
    bcomb[(b << 7) + co] = a0 * bias[co] + a1 * bias[128 + co]
                         + a2 * bias[256 + co] + a3 * bias[384 + co];
  }

  u16* wob = wcomb + (size_t)b * 147456;
  for (int gi = tid; gi < 288; gi += 256){  // 2co * 9tap * (4q*4g) granules
    const int co_l = gi / 144;
    const int r = gi - co_l * 144;
    const int tap = r >> 4;
    const int gg = r & 15;
    const int q = gg >> 2, g = gg & 3;
    const int co = (cp << 1) + co_l;
    union { u16 h[8]; uint4 v; } pk;
    #pragma unroll
    for (int e = 0; e < 8; ++e){
      const int ci = (q << 5) + (g << 3) + e;
      const int j = ci * 9 + tap;
      float s = a0 * wlds[co_l * 1152 + j]        + a1 * wlds[2304 + co_l * 1152 + j]
              + a2 * wlds[4608 + co_l * 1152 + j] + a3 * wlds[6912 + co_l * 1152 + j];
      pk.h[e] = f2bf(s);
    }
    *(uint4*)(wob + (((tap << 2) + q) << 12) + (co << 5) + (g << 3)) = pk.v;
  }
}

// ---------------------------------------------------------------------------
// Kernel 3 (v16): BARRIER-LIGHT conv. Each wave stages its OWN A-half-slab
// (4KB) into a PRIVATE double-buffered LDS region -> zero cross-wave W
// dependency -> no per-step barriers. Only 5 barriers total (prologue + 3
// quarter boundaries for the cooperative X tile + implicit epilogue).
// Per-wave FIFO ledger (incl. X=5 wave0): issue W(s+1):4 at step top, then
//   s==35 -> vmcnt(0); q<3 && tap in {5,6} -> vmcnt(8); else vmcnt(4).
// X dbuf staged at tap5 (inactive buffer); landed by each wave's t7 wait;
// quarter-end BAR gives cross-wave visibility. Waves free-run within a
// quarter (m114 overlap). LDS 33792 + 32768 = 66560B -> 2 blocks/CU.
// grid 512 x 256 thr, b homed to XCD b%8.
// ---------------------------------------------------------------------------
__global__ __launch_bounds__(256, 2) void conv_mfma(
    const u16* __restrict__ xT2, const u16* __restrict__ wcomb,
    const float* __restrict__ bcomb, float* __restrict__ out)
{
  extern __shared__ char smem[];
  u16* s_x = (u16*)smem;               // 2 bufs x 8448 u16 (33792B)
  u16* s_w = (u16*)(smem + 33792);     // 4 waves x 2 bufs x 2048 u16 (32768B)

  const int tid = threadIdx.x;
  const int lane = tid & 63, wid = tid >> 6;
  const int wr = wid & 1, wcv = wid >> 1;    // wr: h-row, wcv: co-half
  const int l15 = lane & 15, hi = lane >> 4;

  const int bid = blockIdx.x;
  const int b = bid & 15;                    // bid%8 == b%8 (L2 homing)
  const int h0 = (bid >> 4) << 1;            // 2 output rows

  const u16* Abase = wcomb + (size_t)b * 147456;
  const u16* Xbase = xT2 + (size_t)b * XB_STRIDE;

#define STAGE_X(Q) { \
    u16* _sx = s_x + ((Q) & 1) * 8448; \
    _Pragma("unroll") \
    for (int _it = 0; _it < 5; ++_it){ \
      const int _G = _it * 256 + tid; \
      if (_it < 4 || _G < 1056){ \
        const int _oct = _G & 3, _t = _G >> 2; \
        const int _col = _t % 66, _row = _t / 66; \
        const u16* _src = Xbase + (h0 + _row) * XR_STRIDE + (_col << 7) \
                        + ((Q) << 5) + (_oct << 3); \
        GLD_LDS(_src, _sx + (_G << 3)); \
      } \
    } }

  // per-wave: stage own wcv half-slab (4KB = 256 granules) into private buf
#define STAGE_W(Q, TAP, BUF) { \
    const u16* _As = Abase + ((((TAP) << 2) + (Q)) << 12) + (wcv << 11); \
    u16* _sw = s_w + (wid << 12) + ((BUF) << 11); \
    _Pragma("unroll") \
    for (int _it = 0; _it < 4; ++_it){ \
      const int _g = (_it << 6) + lane; \
      GLD_LDS(_As + (_g << 3), _sw + (_g << 3)); \
    } }

#define COMPUTE(Q, TAP, BUF) { \
    const int _dh = (TAP) / 3, _dw = (TAP) - 3 * (_dh); \
    const u16* _sw = s_w + (wid << 12) + ((BUF) << 11); \
    const u16* _sx = s_x + ((Q) & 1) * 8448; \
    short8 _af[4], _bf[4]; \
    _Pragma("unroll") \
    for (int _a = 0; _a < 4; ++_a){ \
      const int _cl = (_a << 4) + l15; \
      _af[_a] = *(const short8*)(_sw + (_cl << 5) + (hi << 3)); \
    } \
    _Pragma("unroll") \
    for (int _p = 0; _p < 4; ++_p){ \
      const int _col = l15 + _dw + (_p << 4); \
      _bf[_p] = *(const short8*)(_sx + (((wr + _dh) * 66 + _col) << 5) + (hi << 3)); \
    } \
    _Pragma("unroll") \
    for (int _a = 0; _a < 4; ++_a) \
      _Pragma("unroll") \
      for (int _p = 0; _p < 4; ++_p) \
        acc[_a][_p] = __builtin_amdgcn_mfma_f32_16x16x32_bf16(_af[_a], _bf[_p], acc[_a][_p], 0, 0, 0); }

  f32x4 acc[4][4] = {};

  // prologue
  STAGE_X(0);
  STAGE_W(0, 0, 0);
  WAIT_VM(0);
  __syncthreads();

  for (int q = 0; q < 4; ++q){
    #pragma unroll
    for (int tap = 0; tap < 9; ++tap){
      const int s = q * 9 + tap;
      if (s < 35){
        const int nq = (tap == 8) ? q + 1 : q;
        const int nt = (tap == 8) ? 0 : tap + 1;
        STAGE_W(nq, nt, (s + 1) & 1);
      }
      if (tap == 5 && q < 3){ STAGE_X(q + 1); }
      // per-wave FIFO waits (see ledger in header)
      if (s == 35)                             { WAIT_VM(0); }
      else if (q < 3 && (tap == 5 || tap == 6)){ WAIT_VM(8); }
      else                                     { WAIT_VM(4); }
      __builtin_amdgcn_s_setprio(1);
      COMPUTE(q, tap, s & 1);
      __builtin_amdgcn_s_setprio(0);
      if (tap == 8 && q < 3){ BAR; }   // quarter boundary: X visibility
    }
  }

#undef COMPUTE
#undef STAGE_W
#undef STAGE_X

  // ---- epilogue: C/D col=l15 (w), row=hi*4+r (co). NT stores. ----
  const int hrow = h0 + wr;
  float* ob = out + ((size_t)b << 19) + (hrow << 6) + l15;
  #pragma unroll
  for (int a = 0; a < 4; ++a){
    const int co0 = (wcv << 6) + (a << 4) + (hi << 2);
    #pragma unroll
    for (int r = 0; r < 4; ++r){
      const float bc = bcomb[(b << 7) + co0 + r];
      float* op = ob + (size_t)(co0 + r) * 4096;
      #pragma unroll
      for (int p = 0; p < 4; ++p)
        __builtin_nontemporal_store(acc[a][p][r] + bc, op + (p << 4));
    }
  }
}

// ---------------------------------------------------------------------------
extern "C" void kernel_launch(void* const* d_in, const int* in_sizes, int n_in,
                              void* d_out, int out_size, void* d_ws, size_t ws_size,
                              hipStream_t stream)
{
  const float* x    = (const float*)d_in[0];
  const float* W    = (const float*)d_in[1];
  const float* bias = (const float*)d_in[2];
  const float* w1   = (const float*)d_in[3];
  const float* w2   = (const float*)d_in[4];
  const float* b2   = (const float*)d_in[5];
  float* out = (float*)d_out;

  char* ws = (char*)d_ws;
  float* part  = (float*)(ws);               // 16*64*128*4 = 524288 B
  float* bcomb = (float*)(ws + 524288);      // 8192 B
  u16*   xT2   = (u16*)  (ws + 532480);      // 17,842,176 B
  u16*   wcomb = (u16*)  (ws + 18374656);    // 4,718,592 B (end ~23.1 MB)

  xpose_pool<<<1024, 256, 0, stream>>>(x, xT2, part);
  combine<<<1024, 256, 0, stream>>>(W, bias, part, w1, w2, b2, wcomb, bcomb);

  (void)hipFuncSetAttribute(reinterpret_cast<const void*>(conv_mfma),
                            hipFuncAttributeMaxDynamicSharedMemorySize, 66560);
  conv_mfma<<<512, 256, 66560, stream>>>(xT2, wcomb, bcomb, out);
}

// Round 20
// 47.397 us; speedup vs baseline: 1.0467x; 1.0467x over previous
//
#include <hip/hip_runtime.h>
#include <cstdint>
#include <cstddef>

typedef unsigned short u16;
typedef __attribute__((ext_vector_type(8))) short short8;
typedef __attribute__((ext_vector_type(4))) float f32x4;

__device__ __forceinline__ u16 f2bf(float f){
  union { float f; unsigned u; } c; c.f = f;
  unsigned u = c.u;
  u += 0x7fffu + ((u >> 16) & 1u);   // RNE
  return (u16)(u >> 16);
}
__device__ __forceinline__ unsigned pk2(float a, float b){
  union { float f; unsigned u; } ca, cb; ca.f = a; cb.f = b;
  return ((ca.u + 0x8000u) >> 16) | ((cb.u + 0x8000u) & 0xFFFF0000u);
}

// xT2 layout: [b][row 0..65][col 0..65][128ci] bf16, interior at (h+1, w+1).
#define XB_STRIDE 557568   // 66*66*128 (u16 elements)
#define XR_STRIDE 8448     // 66*128

// wcomb layout (v17, u16): b*147456 + s*4096 + wcv*2048 + a*512 + hi*128
//   + l15*8 + e,  where s = q*9+tap (step), co = wcv*64+a*16+l15,
//   ci = q*32+hi*8+e.  Each (s,wcv,a) A-frag = contiguous 1KB -> a wave's
//   global_load_dwordx4 of it is perfectly coalesced (A read direct to VGPR).

// direct-to-LDS 16B async copy
#define GLD_LDS(gsrc, ldst) \
  __builtin_amdgcn_global_load_lds((const __attribute__((address_space(1))) void*)(gsrc), \
                                   (__attribute__((address_space(3))) void*)(ldst), 16, 0, 0)

#define BAR { asm volatile("s_waitcnt lgkmcnt(0)" ::: "memory"); \
              __builtin_amdgcn_s_barrier(); }
#define WAIT_VM(N) asm volatile("s_waitcnt vmcnt(" #N ")" ::: "memory")

// ---------------------------------------------------------------------------
// Kernel 1 (r18 version): transpose x -> padded xT2 bf16 + SE pool partials.
// grid 1024 (4 blocks/CU), b = bid&15 (bid%8==b%8 homing).
// ---------------------------------------------------------------------------
__global__ __launch_bounds__(256) void xpose_pool(
    const float* __restrict__ x, u16* __restrict__ xT2, float* __restrict__ part)
{
  const int bid = blockIdx.x;
  const int b = bid & 15, chunk = bid >> 4;   // chunk 0..63
  const int pos0 = chunk << 6;
  const int tid = threadIdx.x;
  __shared__ u16 tile[8192];         // 16 KB
  __shared__ float psum[128 * 17];   // 8.7 KB
  const float* xb = x + ((size_t)b << 19) + pos0;
  const int rq = tid & 15;           // row-quad
  const int p4 = rq << 2;
  const int gci = tid >> 4;          // granule 0..15

  if (chunk == 0){                   // fused halo zeroing (disjoint from interior)
    u16* xh = xT2 + (size_t)b * XB_STRIDE;
    for (int i = tid; i < 4160; i += 256){     // 260 pos * 16 granules
      const int p = i >> 4, oct = i & 15;
      int row, col;
      if (p < 66)      { row = 0;        col = p; }
      else if (p < 132){ row = 65;       col = p - 66; }
      else if (p < 196){ row = p - 131;  col = 0; }
      else             { row = p - 195;  col = 65; }
      *(uint4*)(xh + row * XR_STRIDE + (col << 7) + (oct << 3)) =
          make_uint4(0u, 0u, 0u, 0u);
    }
  }

  {
    const int ci8 = gci << 3;
    float4 L[8];
    #pragma unroll
    for (int j = 0; j < 8; ++j)
      L[j] = *(const float4*)(xb + ((size_t)(ci8 + j) << 12) + p4);
    #pragma unroll
    for (int j = 0; j < 8; ++j)
      psum[(ci8 + j) * 17 + rq] = L[j].x + L[j].y + L[j].z + L[j].w;
    const int gs = gci ^ (rq & 7);
    const float* e = (const float*)L;
    #pragma unroll
    for (int p = 0; p < 4; ++p){
      const int row = p4 + p;
      uint4 V;
      V.x = pk2(e[0 * 4 + p], e[1 * 4 + p]);
      V.y = pk2(e[2 * 4 + p], e[3 * 4 + p]);
      V.z = pk2(e[4 * 4 + p], e[5 * 4 + p]);
      V.w = pk2(e[6 * 4 + p], e[7 * 4 + p]);
      *(uint4*)(tile + (row << 7) + (gs << 3)) = V;
    }
  }
  __syncthreads();

  if (tid < 128){
    float s = 0.f;
    #pragma unroll
    for (int j = 0; j < 16; ++j) s += psum[tid * 17 + j];
    part[(((b << 6) | chunk) << 7) + tid] = s;
  }

  u16* xo = xT2 + (size_t)b * XB_STRIDE;
  const int g = tid & 15, rb = (tid >> 4) << 2;
  #pragma unroll
  for (int r = 0; r < 4; ++r){
    const int row = rb + r;
    const int gs = g ^ ((row >> 2) & 7);
    uint4 v = *(const uint4*)(tile + (row << 7) + (gs << 3));
    const int pos = pos0 + row;
    const int h = pos >> 6, w = pos & 63;
    *(uint4*)(xo + (h + 1) * XR_STRIDE + ((w + 1) << 7) + (g << 3)) = v;
  }
}

// ---------------------------------------------------------------------------
// Kernel 2: combine + inline attn (r18 body); ONLY the wcomb write address
// map changed to the v17 step-major contiguous-frag layout.
// grid 1024 = cp(64 co-pairs)*16 + b (bid%8==b%8 homing).
// ---------------------------------------------------------------------------
__global__ __launch_bounds__(256) void combine(
    const float* __restrict__ W, const float* __restrict__ bias,
    const float* __restrict__ part, const float* __restrict__ w1,
    const float* __restrict__ w2, const float* __restrict__ b2,
    u16* __restrict__ wcomb, float* __restrict__ bcomb)
{
  __shared__ float wlds[9216];   // [k][co_l][1152]
  __shared__ float sp[128];
  __shared__ float sh[33];
  __shared__ float sat[4];
  const int bid = blockIdx.x;
  const int b = bid & 15, cp = bid >> 4;    // cp: co-pair 0..63
  const int tid = threadIdx.x;

  #pragma unroll
  for (int it = 0; it < 9; ++it){
    const int G = it * 256 + tid;
    const int k = G / 576, rem = G - k * 576;
    const int co_l = rem / 288, j4 = rem - co_l * 288;
    const float* src = W + (size_t)(k * 128 + (cp << 1) + co_l) * 1152 + (j4 << 2);
    GLD_LDS(src, (char*)wlds + (G << 4));
  }

  // ---- inline attn[b]: pool (64 chunks) -> fc1 -> relu -> fc2 -> softmax ----
  if (tid < 128){
    const float* pb = part + (b << 13);
    float s = 0.f;
    #pragma unroll 8
    for (int c = 0; c < 64; ++c) s += pb[(c << 7) + tid];
    sp[tid] = s * (1.f / 4096.f);
  }
  __syncthreads();
  if (tid < 33){
    float h = 0.f;
    for (int ci = 0; ci < 128; ++ci) h += sp[ci] * w1[tid * 128 + ci];
    sh[tid] = fmaxf(h, 0.f);
  }
  __syncthreads();
  if (tid == 0){
    float l[4];
    #pragma unroll
    for (int t = 0; t < 4; ++t){
      float v = b2[t];
      for (int j = 0; j < 33; ++j) v += sh[j] * w2[t * 33 + j];
      l[t] = v * (1.f / 30.f);
    }
    float m = fmaxf(fmaxf(l[0], l[1]), fmaxf(l[2], l[3]));
    float e0 = __expf(l[0] - m), e1 = __expf(l[1] - m);
    float e2 = __expf(l[2] - m), e3 = __expf(l[3] - m);
    float inv = 1.f / (e0 + e1 + e2 + e3);
    sat[0] = e0 * inv; sat[1] = e1 * inv; sat[2] = e2 * inv; sat[3] = e3 * inv;
  }
  asm volatile("s_waitcnt vmcnt(0)" ::: "memory");
  __syncthreads();
  const float a0 = sat[0], a1 = sat[1], a2 = sat[2], a3 = sat[3];

  if (tid < 2){
    const int co = (cp << 1) + tid;
    bcomb[(b << 7) + co] = a0 * bias[co] + a1 * bias[128 + co]
                         + a2 * bias[256 + co] + a3 * bias[384 + co];
  }

  u16* wob = wcomb + (size_t)b * 147456;
  for (int gi = tid; gi < 288; gi += 256){  // 2co * 9tap * (4q*4hi) granules
    const int co_l = gi / 144;
    const int r = gi - co_l * 144;
    const int tap = r >> 4;
    const int gg = r & 15;
    const int q = gg >> 2, g = gg & 3;      // g = hi (koct within quarter)
    const int co = (cp << 1) + co_l;
    union { u16 h[8]; uint4 v; } pk;
    #pragma unroll
    for (int e = 0; e < 8; ++e){
      const int ci = (q << 5) + (g << 3) + e;
      const int j = ci * 9 + tap;
      float s = a0 * wlds[co_l * 1152 + j]        + a1 * wlds[2304 + co_l * 1152 + j]
              + a2 * wlds[4608 + co_l * 1152 + j] + a3 * wlds[6912 + co_l * 1152 + j];
      pk.h[e] = f2bf(s);
    }
    // v17 addr: s*4096 + wcv*2048 + a*512 + hi*128 + l15*8
    const int st = q * 9 + tap;
    *(uint4*)(wob + (st << 12) + ((co >> 6) << 11) + (((co >> 4) & 3) << 9)
                  + (g << 7) + ((co & 15) << 3)) = pk.v;
  }
}

// ---------------------------------------------------------------------------
// Kernel 3 (v17): A-frags DIRECT global->VGPR (contiguous 1KB per frag,
// perfectly coalesced, homed-L2-hot), double-buffered in regs, fully
// unrolled 36 steps (static indices). LDS = X only (2 x 16896B dbuf).
// LDS reads halve (4 b128/step/wave); W staging + its vmcnt ledger gone;
// 4 barriers total. Compiler auto-inserts counted waits for A reg-loads.
// grid 512 x 256 thr (4 waves), b homed to XCD b%8.
// ---------------------------------------------------------------------------
__global__ __launch_bounds__(256, 2) void conv_mfma(
    const u16* __restrict__ xT2, const u16* __restrict__ wcomb,
    const float* __restrict__ bcomb, float* __restrict__ out)
{
  extern __shared__ char smem[];
  u16* s_x = (u16*)smem;               // 2 bufs x 8448 u16 (33792B)

  const int tid = threadIdx.x;
  const int lane = tid & 63, wid = tid >> 6;
  const int wr = wid & 1, wcv = wid >> 1;    // wr: h-row, wcv: co-half
  const int l15 = lane & 15, hi = lane >> 4;

  const int bid = blockIdx.x;
  const int b = bid & 15;                    // bid%8 == b%8 (L2 homing)
  const int h0 = (bid >> 4) << 1;            // 2 output rows

  // per-lane A base: + s*4096 per step, + a*512 per frag
  const u16* Ab = wcomb + (size_t)b * 147456 + (wcv << 11) + (hi << 7) + (l15 << 3);
  const u16* Xbase = xT2 + (size_t)b * XB_STRIDE;

#define STAGE_X(Q) { \
    u16* _sx = s_x + ((Q) & 1) * 8448; \
    _Pragma("unroll") \
    for (int _it = 0; _it < 5; ++_it){ \
      const int _G = _it * 256 + tid; \
      if (_it < 4 || _G < 1056){ \
        const int _oct = _G & 3, _t = _G >> 2; \
        const int _col = _t % 66, _row = _t / 66; \
        const u16* _src = Xbase + (h0 + _row) * XR_STRIDE + (_col << 7) \
                        + ((Q) << 5) + (_oct << 3); \
        GLD_LDS(_src, _sx + (_G << 3)); \
      } \
    } }

#define LOAD_A(S, BUF) { \
    const u16* _as = Ab + ((S) << 12); \
    af[BUF][0] = *(const short8*)(_as); \
    af[BUF][1] = *(const short8*)(_as + 512); \
    af[BUF][2] = *(const short8*)(_as + 1024); \
    af[BUF][3] = *(const short8*)(_as + 1536); }

#define COMPUTE(Q, TAP, BUF) { \
    const int _dh = (TAP) / 3, _dw = (TAP) - 3 * (_dh); \
    const u16* _sx = s_x + ((Q) & 1) * 8448; \
    short8 _bf[4]; \
    _Pragma("unroll") \
    for (int _p = 0; _p < 4; ++_p){ \
      const int _col = l15 + _dw + (_p << 4); \
      _bf[_p] = *(const short8*)(_sx + (((wr + _dh) * 66 + _col) << 5) + (hi << 3)); \
    } \
    _Pragma("unroll") \
    for (int _a = 0; _a < 4; ++_a) \
      _Pragma("unroll") \
      for (int _p = 0; _p < 4; ++_p) \
        acc[_a][_p] = __builtin_amdgcn_mfma_f32_16x16x32_bf16(af[BUF][_a], _bf[_p], acc[_a][_p], 0, 0, 0); }

  f32x4 acc[4][4] = {};
  short8 af[2][4];

  // prologue: X(0) staged; A(step0) in flight
  STAGE_X(0);
  LOAD_A(0, 0);
  WAIT_VM(0);
  __syncthreads();

  // fully unrolled 36 steps: all af/buffer indices compile-time (rule #20)
#define STEP(Q, TAP) { \
    const int _s = (Q) * 9 + (TAP); \
    if (_s < 35) LOAD_A(_s + 1, ((_s + 1) & 1)); \
    if ((TAP) == 5 && (Q) < 3) STAGE_X((Q) + 1); \
    __builtin_amdgcn_s_setprio(1); \
    COMPUTE(Q, TAP, (_s & 1)); \
    __builtin_amdgcn_s_setprio(0); \
    if ((TAP) == 8 && (Q) < 3){ WAIT_VM(0); BAR; } }

  STEP(0,0) STEP(0,1) STEP(0,2) STEP(0,3) STEP(0,4) STEP(0,5) STEP(0,6) STEP(0,7) STEP(0,8)
  STEP(1,0) STEP(1,1) STEP(1,2) STEP(1,3) STEP(1,4) STEP(1,5) STEP(1,6) STEP(1,7) STEP(1,8)
  STEP(2,0) STEP(2,1) STEP(2,2) STEP(2,3) STEP(2,4) STEP(2,5) STEP(2,6) STEP(2,7) STEP(2,8)
  STEP(3,0) STEP(3,1) STEP(3,2) STEP(3,3) STEP(3,4) STEP(3,5) STEP(3,6) STEP(3,7) STEP(3,8)

#undef STEP
#undef COMPUTE
#undef LOAD_A
#undef STAGE_X

  // ---- epilogue: C/D col=l15 (w), row=hi*4+r (co). NT stores. ----
  const int hrow = h0 + wr;
  float* ob = out + ((size_t)b << 19) + (hrow << 6) + l15;
  #pragma unroll
  for (int a = 0; a < 4; ++a){
    const int co0 = (wcv << 6) + (a << 4) + (hi << 2);
    #pragma unroll
    for (int r = 0; r < 4; ++r){
      const float bc = bcomb[(b << 7) + co0 + r];
      float* op = ob + (size_t)(co0 + r) * 4096;
      #pragma unroll
      for (int p = 0; p < 4; ++p)
        __builtin_nontemporal_store(acc[a][p][r] + bc, op + (p << 4));
    }
  }
}

// ---------------------------------------------------------------------------
extern "C" void kernel_launch(void* const* d_in, const int* in_sizes, int n_in,
                              void* d_out, int out_size, void* d_ws, size_t ws_size,
                              hipStream_t stream)
{
  const float* x    = (const float*)d_in[0];
  const float* W    = (const float*)d_in[1];
  const float* bias = (const float*)d_in[2];
  const float* w1   = (const float*)d_in[3];
  const float* w2   = (const float*)d_in[4];
  const float* b2   = (const float*)d_in[5];
  float* out = (float*)d_out;

  char* ws = (char*)d_ws;
  float* part  = (float*)(ws);               // 16*64*128*4 = 524288 B
  float* bcomb = (float*)(ws + 524288);      // 8192 B
  u16*   xT2   = (u16*)  (ws + 532480);      // 17,842,176 B
  u16*   wcomb = (u16*)  (ws + 18374656);    // 4,718,592 B (end ~23.1 MB)

  xpose_pool<<<1024, 256, 0, stream>>>(x, xT2, part);
  combine<<<1024, 256, 0, stream>>>(W, bias, part, w1, w2, b2, wcomb, bcomb);

  (void)hipFuncSetAttribute(reinterpret_cast<const void*>(conv_mfma),
                            hipFuncAttributeMaxDynamicSharedMemorySize, 33792);
  conv_mfma<<<512, 256, 33792, stream>>>(xT2, wcomb, bcomb, out);
}

// Round 21
// 46.440 us; speedup vs baseline: 1.0682x; 1.0206x over previous
//
#include <hip/hip_runtime.h>
#include <cstdint>
#include <cstddef>

typedef unsigned short u16;
typedef __attribute__((ext_vector_type(8))) short short8;
typedef __attribute__((ext_vector_type(4))) float f32x4;

__device__ __forceinline__ u16 f2bf(float f){
  union { float f; unsigned u; } c; c.f = f;
  unsigned u = c.u;
  u += 0x7fffu + ((u >> 16) & 1u);   // RNE
  return (u16)(u >> 16);
}
__device__ __forceinline__ unsigned pk2(float a, float b){
  union { float f; unsigned u; } ca, cb; ca.f = a; cb.f = b;
  return ((ca.u + 0x8000u) >> 16) | ((cb.u + 0x8000u) & 0xFFFF0000u);
}

// xT2 layout: [b][row 0..65][col 0..65][128ci] bf16, interior at (h+1, w+1).
#define XB_STRIDE 557568   // 66*66*128 (u16 elements)
#define XR_STRIDE 8448     // 66*128

// wcomb layout (v17, u16): b*147456 + s*4096 + wcv2*2048 + a2*512 + hi*128
//   + l15*8 + e,  s = q*9+tap, co = wcv2*64 + a2*16 + l15, ci = q*32+hi*8+e.
//   v18 reads it as: per co-quarter wave wcv (0..3), A base = wcv*1024,
//   frags at +0,+512 (a2 = wcv&1 ? {2,3} : {0,1} folds into the same map).

// direct-to-LDS 16B async copy
#define GLD_LDS(gsrc, ldst) \
  __builtin_amdgcn_global_load_lds((const __attribute__((address_space(1))) void*)(gsrc), \
                                   (__attribute__((address_space(3))) void*)(ldst), 16, 0, 0)

#define BAR { asm volatile("s_waitcnt lgkmcnt(0)" ::: "memory"); \
              __builtin_amdgcn_s_barrier(); }
#define WAIT_VM(N) asm volatile("s_waitcnt vmcnt(" #N ")" ::: "memory")

// ---------------------------------------------------------------------------
// Kernel 1 (r18 version): transpose x -> padded xT2 bf16 + SE pool partials.
// grid 1024 (4 blocks/CU), b = bid&15 (bid%8==b%8 homing).
// ---------------------------------------------------------------------------
__global__ __launch_bounds__(256) void xpose_pool(
    const float* __restrict__ x, u16* __restrict__ xT2, float* __restrict__ part)
{
  const int bid = blockIdx.x;
  const int b = bid & 15, chunk = bid >> 4;   // chunk 0..63
  const int pos0 = chunk << 6;
  const int tid = threadIdx.x;
  __shared__ u16 tile[8192];         // 16 KB
  __shared__ float psum[128 * 17];   // 8.7 KB
  const float* xb = x + ((size_t)b << 19) + pos0;
  const int rq = tid & 15;           // row-quad
  const int p4 = rq << 2;
  const int gci = tid >> 4;          // granule 0..15

  if (chunk == 0){                   // fused halo zeroing (disjoint from interior)
    u16* xh = xT2 + (size_t)b * XB_STRIDE;
    for (int i = tid; i < 4160; i += 256){     // 260 pos * 16 granules
      const int p = i >> 4, oct = i & 15;
      int row, col;
      if (p < 66)      { row = 0;        col = p; }
      else if (p < 132){ row = 65;       col = p - 66; }
      else if (p < 196){ row = p - 131;  col = 0; }
      else             { row = p - 195;  col = 65; }
      *(uint4*)(xh + row * XR_STRIDE + (col << 7) + (oct << 3)) =
          make_uint4(0u, 0u, 0u, 0u);
    }
  }

  {
    const int ci8 = gci << 3;
    float4 L[8];
    #pragma unroll
    for (int j = 0; j < 8; ++j)
      L[j] = *(const float4*)(xb + ((size_t)(ci8 + j) << 12) + p4);
    #pragma unroll
    for (int j = 0; j < 8; ++j)
      psum[(ci8 + j) * 17 + rq] = L[j].x + L[j].y + L[j].z + L[j].w;
    const int gs = gci ^ (rq & 7);
    const float* e = (const float*)L;
    #pragma unroll
    for (int p = 0; p < 4; ++p){
      const int row = p4 + p;
      uint4 V;
      V.x = pk2(e[0 * 4 + p], e[1 * 4 + p]);
      V.y = pk2(e[2 * 4 + p], e[3 * 4 + p]);
      V.z = pk2(e[4 * 4 + p], e[5 * 4 + p]);
      V.w = pk2(e[6 * 4 + p], e[7 * 4 + p]);
      *(uint4*)(tile + (row << 7) + (gs << 3)) = V;
    }
  }
  __syncthreads();

  if (tid < 128){
    float s = 0.f;
    #pragma unroll
    for (int j = 0; j < 16; ++j) s += psum[tid * 17 + j];
    part[(((b << 6) | chunk) << 7) + tid] = s;
  }

  u16* xo = xT2 + (size_t)b * XB_STRIDE;
  const int g = tid & 15, rb = (tid >> 4) << 2;
  #pragma unroll
  for (int r = 0; r < 4; ++r){
    const int row = rb + r;
    const int gs = g ^ ((row >> 2) & 7);
    uint4 v = *(const uint4*)(tile + (row << 7) + (gs << 3));
    const int pos = pos0 + row;
    const int h = pos >> 6, w = pos & 63;
    *(uint4*)(xo + (h + 1) * XR_STRIDE + ((w + 1) << 7) + (g << 3)) = v;
  }
}

// ---------------------------------------------------------------------------
// Kernel 2 (r20 version): combine + inline attn; v17 step-major wcomb writes.
// grid 1024 = cp(64 co-pairs)*16 + b (bid%8==b%8 homing).
// ---------------------------------------------------------------------------
__global__ __launch_bounds__(256) void combine(
    const float* __restrict__ W, const float* __restrict__ bias,
    const float* __restrict__ part, const float* __restrict__ w1,
    const float* __restrict__ w2, const float* __restrict__ b2,
    u16* __restrict__ wcomb, float* __restrict__ bcomb)
{
  __shared__ float wlds[9216];   // [k][co_l][1152]
  __shared__ float sp[128];
  __shared__ float sh[33];
  __shared__ float sat[4];
  const int bid = blockIdx.x;
  const int b = bid & 15, cp = bid >> 4;    // cp: co-pair 0..63
  const int tid = threadIdx.x;

  #pragma unroll
  for (int it = 0; it < 9; ++it){
    const int G = it * 256 + tid;
    const int k = G / 576, rem = G - k * 576;
    const int co_l = rem / 288, j4 = rem - co_l * 288;
    const float* src = W + (size_t)(k * 128 + (cp << 1) + co_l) * 1152 + (j4 << 2);
    GLD_LDS(src, (char*)wlds + (G << 4));
  }

  // ---- inline attn[b]: pool (64 chunks) -> fc1 -> relu -> fc2 -> softmax ----
  if (tid < 128){
    const float* pb = part + (b << 13);
    float s = 0.f;
    #pragma unroll 8
    for (int c = 0; c < 64; ++c) s += pb[(c << 7) + tid];
    sp[tid] = s * (1.f / 4096.f);
  }
  __syncthreads();
  if (tid < 33){
    float h = 0.f;
    for (int ci = 0; ci < 128; ++ci) h += sp[ci] * w1[tid * 128 + ci];
    sh[tid] = fmaxf(h, 0.f);
  }
  __syncthreads();
  if (tid == 0){
    float l[4];
    #pragma unroll
    for (int t = 0; t < 4; ++t){
      float v = b2[t];
      for (int j = 0; j < 33; ++j) v += sh[j] * w2[t * 33 + j];
      l[t] = v * (1.f / 30.f);
    }
    float m = fmaxf(fmaxf(l[0], l[1]), fmaxf(l[2], l[3]));
    float e0 = __expf(l[0] - m), e1 = __expf(l[1] - m);
    float e2 = __expf(l[2] - m), e3 = __expf(l[3] - m);
    float inv = 1.f / (e0 + e1 + e2 + e3);
    sat[0] = e0 * inv; sat[1] = e1 * inv; sat[2] = e2 * inv; sat[3] = e3 * inv;
  }
  asm volatile("s_waitcnt vmcnt(0)" ::: "memory");
  __syncthreads();
  const float a0 = sat[0], a1 = sat[1], a2 = sat[2], a3 = sat[3];

  if (tid < 2){
    const int co = (cp << 1) + tid;
    bcomb[(b << 7) + co] = a0 * bias[co] + a1 * bias[128 + co]
                         + a2 * bias[256 + co] + a3 * bias[384 + co];
  }

  u16* wob = wcomb + (size_t)b * 147456;
  for (int gi = tid; gi < 288; gi += 256){  // 2co * 9tap * (4q*4hi) granules
    const int co_l = gi / 144;
    const int r = gi - co_l * 144;
    const int tap = r >> 4;
    const int gg = r & 15;
    const int q = gg >> 2, g = gg & 3;      // g = hi
    const int co = (cp << 1) + co_l;
    union { u16 h[8]; uint4 v; } pk;
    #pragma unroll
    for (int e = 0; e < 8; ++e){
      const int ci = (q << 5) + (g << 3) + e;
      const int j = ci * 9 + tap;
      float s = a0 * wlds[co_l * 1152 + j]        + a1 * wlds[2304 + co_l * 1152 + j]
              + a2 * wlds[4608 + co_l * 1152 + j] + a3 * wlds[6912 + co_l * 1152 + j];
      pk.h[e] = f2bf(s);
    }
    const int st = q * 9 + tap;
    *(uint4*)(wob + (st << 12) + ((co >> 6) << 11) + (((co >> 4) & 3) << 9)
                  + (g << 7) + ((co & 15) << 3)) = pk.v;
  }
}

// ---------------------------------------------------------------------------
// Kernel 3 (v18): r20's A-direct-to-VGPR conv at 4 WAVES/SIMD. grid 1024
// (16 b x 64 h-rows, homing kept), 1 output row/block, 4 waves = co-quarters
// (wave = 32co x 64pos, acc[2][4]). LDS: X only, 3row x 66col x 32ci per
// quarter (12672B), dbuf = 25344B -> 4 blocks/CU; launch_bounds(256,4)
// caps VGPR<=128. A traffic unchanged vs r20 (each co loaded once/block).
// Schedule identical: A reg-dbuf, X dbuf at tap5, WAIT_VM(0)+BAR at 3
// quarter boundaries only.
// ---------------------------------------------------------------------------
__global__ __launch_bounds__(256, 4) void conv_mfma(
    const u16* __restrict__ xT2, const u16* __restrict__ wcomb,
    const float* __restrict__ bcomb, float* __restrict__ out)
{
  extern __shared__ char smem[];
  u16* s_x = (u16*)smem;               // 2 bufs x 6336 u16 (25344B total)

  const int tid = threadIdx.x;
  const int lane = tid & 63, wcv = tid >> 6;   // wave = co-quarter 0..3
  const int l15 = lane & 15, hi = lane >> 4;

  const int bid = blockIdx.x;
  const int b = bid & 15;                    // bid%8 == b%8 (L2 homing)
  const int h0 = bid >> 4;                   // output row 0..63

  // per-lane A base: + s*4096 per step; frags at +0, +512
  const u16* Ab = wcomb + (size_t)b * 147456 + (wcv << 10) + (hi << 7) + (l15 << 3);
  const u16* Xbase = xT2 + (size_t)b * XB_STRIDE;

#define STAGE_X(Q) { \
    u16* _sx = s_x + ((Q) & 1) * 6336; \
    _Pragma("unroll") \
    for (int _it = 0; _it < 4; ++_it){ \
      const int _G = _it * 256 + tid; \
      if (_it < 3 || _G < 792){ \
        const int _oct = _G & 3, _t = _G >> 2; \
        const int _col = _t % 66, _row = _t / 66; \
        const u16* _src = Xbase + (h0 + _row) * XR_STRIDE + (_col << 7) \
                        + ((Q) << 5) + (_oct << 3); \
        GLD_LDS(_src, _sx + (_G << 3)); \
      } \
    } }

#define LOAD_A(S, BUF) { \
    const u16* _as = Ab + ((S) << 12); \
    af[BUF][0] = *(const short8*)(_as); \
    af[BUF][1] = *(const short8*)(_as + 512); }

#define COMPUTE(Q, TAP, BUF) { \
    const int _dh = (TAP) / 3, _dw = (TAP) - 3 * (_dh); \
    const u16* _sx = s_x + ((Q) & 1) * 6336; \
    short8 _bf[4]; \
    _Pragma("unroll") \
    for (int _p = 0; _p < 4; ++_p){ \
      const int _col = l15 + _dw + (_p << 4); \
      _bf[_p] = *(const short8*)(_sx + ((_dh * 66 + _col) << 5) + (hi << 3)); \
    } \
    _Pragma("unroll") \
    for (int _a = 0; _a < 2; ++_a) \
      _Pragma("unroll") \
      for (int _p = 0; _p < 4; ++_p) \
        acc[_a][_p] = __builtin_amdgcn_mfma_f32_16x16x32_bf16(af[BUF][_a], _bf[_p], acc[_a][_p], 0, 0, 0); }

  f32x4 acc[2][4] = {};
  short8 af[2][2];

  // prologue: X(0) staged; A(step0) in flight
  STAGE_X(0);
  LOAD_A(0, 0);
  WAIT_VM(0);
  __syncthreads();

#define STEP(Q, TAP) { \
    const int _s = (Q) * 9 + (TAP); \
    if (_s < 35) LOAD_A(_s + 1, ((_s + 1) & 1)); \
    if ((TAP) == 5 && (Q) < 3) STAGE_X((Q) + 1); \
    __builtin_amdgcn_s_setprio(1); \
    COMPUTE(Q, TAP, (_s & 1)); \
    __builtin_amdgcn_s_setprio(0); \
    if ((TAP) == 8 && (Q) < 3){ WAIT_VM(0); BAR; } }

  STEP(0,0) STEP(0,1) STEP(0,2) STEP(0,3) STEP(0,4) STEP(0,5) STEP(0,6) STEP(0,7) STEP(0,8)
  STEP(1,0) STEP(1,1) STEP(1,2) STEP(1,3) STEP(1,4) STEP(1,5) STEP(1,6) STEP(1,7) STEP(1,8)
  STEP(2,0) STEP(2,1) STEP(2,2) STEP(2,3) STEP(2,4) STEP(2,5) STEP(2,6) STEP(2,7) STEP(2,8)
  STEP(3,0) STEP(3,1) STEP(3,2) STEP(3,3) STEP(3,4) STEP(3,5) STEP(3,6) STEP(3,7) STEP(3,8)

#undef STEP
#undef COMPUTE
#undef LOAD_A
#undef STAGE_X

  // ---- epilogue: C/D col=l15 (pos), row=hi*4+r (co). NT stores. ----
  float* ob = out + ((size_t)b << 19) + (h0 << 6) + l15;
  #pragma unroll
  for (int a = 0; a < 2; ++a){
    const int co0 = (wcv << 5) + (a << 4) + (hi << 2);
    #pragma unroll
    for (int r = 0; r < 4; ++r){
      const float bc = bcomb[(b << 7) + co0 + r];
      float* op = ob + (size_t)(co0 + r) * 4096;
      #pragma unroll
      for (int p = 0; p < 4; ++p)
        __builtin_nontemporal_store(acc[a][p][r] + bc, op + (p << 4));
    }
  }
}

// ---------------------------------------------------------------------------
extern "C" void kernel_launch(void* const* d_in, const int* in_sizes, int n_in,
                              void* d_out, int out_size, void* d_ws, size_t ws_size,
                              hipStream_t stream)
{
  const float* x    = (const float*)d_in[0];
  const float* W    = (const float*)d_in[1];
  const float* bias = (const float*)d_in[2];
  const float* w1   = (const float*)d_in[3];
  const float* w2   = (const float*)d_in[4];
  const float* b2   = (const float*)d_in[5];
  float* out = (float*)d_out;

  char* ws = (char*)d_ws;
  float* part  = (float*)(ws);               // 16*64*128*4 = 524288 B
  float* bcomb = (float*)(ws + 524288);      // 8192 B
  u16*   xT2   = (u16*)  (ws + 532480);      // 17,842,176 B
  u16*   wcomb = (u16*)  (ws + 18374656);    // 4,718,592 B (end ~23.1 MB)

  xpose_pool<<<1024, 256, 0, stream>>>(x, xT2, part);
  combine<<<1024, 256, 0, stream>>>(W, bias, part, w1, w2, b2, wcomb, bcomb);

  (void)hipFuncSetAttribute(reinterpret_cast<const void*>(conv_mfma),
                            hipFuncAttributeMaxDynamicSharedMemorySize, 25344);
  conv_mfma<<<1024, 256, 25344, stream>>>(xT2, wcomb, bcomb, out);
}